// Round 3
// baseline (952.821 us; speedup 1.0000x reference)
//
#include <hip/hip_runtime.h>
#include <hip/hip_bf16.h>

#define DIN   7686
#define NNODE 7946
#define HOUT  260
#define KPAD  7808   // DIN padded to 244*32
#define NPAD  7808
#define NSTEP 244
#define LDSTR 40     // LDS row stride in shorts

typedef __attribute__((ext_vector_type(8))) short bf16x8;
typedef __attribute__((ext_vector_type(4))) float f32x4;

__device__ __forceinline__ unsigned int f2b(float f) {
  union { float f; unsigned int u; } v; v.f = f;
  return (v.u + 0x7FFFu + ((v.u >> 16) & 1u)) >> 16;  // RNE float->bf16
}
__device__ __forceinline__ unsigned int pack2(float lo, float hi) {
  unsigned int r;
  asm("v_cvt_pk_bf16_f32 %0, %1, %2" : "=v"(r) : "v"(lo), "v"(hi));
  return r;
}
__device__ __forceinline__ float b2f(unsigned short h) {
  union { unsigned int u; float f; } v; v.u = ((unsigned int)h) << 16; return v.f;
}

// ---------------------------------------------------------------------------
// prep: fp32 X -> bf16, padded [256][KPAD] with zeros beyond DIN
// ---------------------------------------------------------------------------
__global__ void prep_x(const float* __restrict__ X, unsigned short* __restrict__ Xb)
{
  const int mrow = blockIdx.x;
  for (int c = threadIdx.x; c < KPAD; c += blockDim.x) {
    float v = (c < DIN) ? X[(size_t)mrow * DIN + c] : 0.f;
    Xb[(size_t)mrow * KPAD + c] = (unsigned short)f2b(v);
  }
}

// ---------------------------------------------------------------------------
// Pipelined GEMM: C_part[m,n] = sum_k A[m,k]*B[n,k]
// A: bf16 [256][lda]. B: fp32 (QKV) or bf16 (LOGITS), converted to bf16.
// BM=256, BN=64, BK=32. 512 thr = 8 waves (4 row-blk x 2 col-blk).
// Register ring (depth 2) + double-buffered LDS + raw s_barrier: loads for
// step k+2 issued at step k stay in flight across barriers (counted vmcnt).
// K-split via blockIdx.z writes per-split partial buffers (NO atomics):
//   QKV:    bf16 partials at Cbase + (mat*gridDim.z+z)*256*ldc
//   LOGITS: fp32 partials at Cbase + z*256*ldc
// ---------------------------------------------------------------------------
template<bool LOGITS>
__global__ __launch_bounds__(512, 4)
void gemm_pipe(const unsigned short* __restrict__ Abf, int lda,
               const void* __restrict__ B0, const void* __restrict__ B1,
               const void* __restrict__ B2,
               long long bClamp, int ldb, int nvalidB,
               void* __restrict__ Cbase, int ldc, int kstepsPer)
{
  const int mat = blockIdx.y;
  const void* Bv = (mat == 0) ? B0 : (mat == 1) ? B1 : B2;
  const int z = blockIdx.z;
  const int n0 = blockIdx.x * 64;
  const int tid = threadIdx.x;
  const int lane = tid & 63;
  const int wv = tid >> 6, wr = wv >> 1, wc = wv & 1;

  __shared__ __align__(16) unsigned short As[2][256 * LDSTR];
  __shared__ __align__(16) unsigned short Bs[2][64 * LDSTR];

  // A: thread -> row tid>>1, 16 shorts (32B) at k-offset (tid&1)*16
  const int aRow = tid >> 1;
  const int aOff = (tid & 1) * 16;
  // B: thread -> row tid>>3, 4 elems at k-slot (tid&7)*4
  int bRow = n0 + (tid >> 3);
  if (bRow >= nvalidB) bRow = nvalidB - 1;
  const long long bOff0 = (long long)bRow * ldb + (tid & 7) * 4;

  uint4  sa00, sa01, sa10, sa11;   // A ring slots (2 x 2 chunks)
  float4 sbf0, sbf1;               // B ring slots (fp32 path)
  uint2  sbh0, sbh1;               // B ring slots (bf16 path)

#define LOADA(s0, s1, kb_) {                                           \
    const unsigned short* ap = Abf + (size_t)aRow * lda + (kb_) + aOff; \
    s0 = *(const uint4*)ap;                                            \
    s1 = *(const uint4*)(ap + 8); }
#define LOADB_F(dst, kb_) {                                            \
    long long idx = bOff0 + (kb_);                                     \
    if (idx > bClamp) idx = bClamp;                                    \
    dst = *(const float4*)((const float*)Bv + idx); }
#define LOADB_H(dst, kb_) {                                            \
    long long idx = bOff0 + (kb_);                                     \
    if (idx > bClamp) idx = bClamp;                                    \
    dst = *(const uint2*)((const unsigned short*)Bv + idx); }
#define LOAD0(kb_) { LOADA(sa00, sa01, kb_)                            \
    if constexpr (LOGITS) LOADB_H(sbh0, kb_) else LOADB_F(sbf0, kb_) }
#define LOAD1(kb_) { LOADA(sa10, sa11, kb_)                            \
    if constexpr (LOGITS) LOADB_H(sbh1, kb_) else LOADB_F(sbf1, kb_) }
#define STAGE(buf, a0, a1, bf_, bh_) {                                 \
    unsigned short* as_ = As[buf];                                     \
    *(uint4*)&as_[aRow * LDSTR + aOff]     = a0;                       \
    *(uint4*)&as_[aRow * LDSTR + aOff + 8] = a1;                       \
    unsigned short* bs_ = Bs[buf];                                     \
    if constexpr (LOGITS) {                                            \
      *(uint2*)&bs_[(tid >> 3) * LDSTR + (tid & 7) * 4] = bh_;         \
    } else {                                                           \
      uint2 o_; o_.x = pack2(bf_.x, bf_.y); o_.y = pack2(bf_.z, bf_.w);\
      *(uint2*)&bs_[(tid >> 3) * LDSTR + (tid & 7) * 4] = o_;          \
    } }
#define BARRIER() {                                                    \
    asm volatile("s_waitcnt lgkmcnt(0)" ::: "memory");                 \
    __builtin_amdgcn_s_barrier();                                      \
    __builtin_amdgcn_sched_barrier(0); }

  f32x4 acc[4][2] = {};
  const int lm = lane & 15;
  const int lq = (lane >> 4) * 8;

  auto COMPUTE = [&](const unsigned short* as_, const unsigned short* bs_) {
    bf16x8 b0 = *(const bf16x8*)&bs_[(wc * 32 + lm) * LDSTR + lq];
    bf16x8 b1 = *(const bf16x8*)&bs_[(wc * 32 + 16 + lm) * LDSTR + lq];
#pragma unroll
    for (int i = 0; i < 4; ++i) {
      bf16x8 a = *(const bf16x8*)&as_[(wr * 64 + i * 16 + lm) * LDSTR + lq];
      acc[i][0] = __builtin_amdgcn_mfma_f32_16x16x32_bf16(a, b0, acc[i][0], 0, 0, 0);
      acc[i][1] = __builtin_amdgcn_mfma_f32_16x16x32_bf16(a, b1, acc[i][1], 0, 0, 0);
    }
  };

  const int kBeg = z * kstepsPer;
  int kcount = NSTEP - kBeg; if (kcount > kstepsPer) kcount = kstepsPer;  // even

  int kb = kBeg * 32;
  LOAD0(kb)
  LOAD1(kb + 32)
  STAGE(0, sa00, sa01, sbf0, sbh0)
  BARRIER()
  for (int s = 0; s < kcount; s += 2) {
    if (s + 2 < kcount) LOAD0(kb + 64)
    STAGE(1, sa10, sa11, sbf1, sbh1)
    COMPUTE(As[0], Bs[0]);
    BARRIER()
    if (s + 3 < kcount) LOAD1(kb + 96)
    if (s + 2 < kcount) STAGE(0, sa00, sa01, sbf0, sbh0)
    COMPUTE(As[1], Bs[1]);
    BARRIER()
    kb += 64;
  }

  // epilogue: plain stores to this split's partial buffer
  void* Cp;
  if constexpr (LOGITS) Cp = (void*)((float*)Cbase + (size_t)z * 256 * ldc);
  else Cp = (void*)((unsigned short*)Cbase + (size_t)(mat * gridDim.z + z) * 256 * ldc);
#pragma unroll
  for (int i = 0; i < 4; ++i) {
    const int r0 = wr * 64 + i * 16 + (lane >> 4) * 4;
#pragma unroll
    for (int j = 0; j < 2; ++j) {
      const int col = n0 + wc * 32 + j * 16 + lm;
#pragma unroll
      for (int q = 0; q < 4; ++q) {
        float v = acc[i][j][q];
        if constexpr (LOGITS) ((float*)Cp)[(size_t)(r0 + q) * ldc + col] = v;
        else ((unsigned short*)Cp)[(size_t)(r0 + q) * ldc + col] = (unsigned short)f2b(v);
      }
    }
  }
#undef LOADA
#undef LOADB_F
#undef LOADB_H
#undef LOAD0
#undef LOAD1
#undef STAGE
#undef BARRIER
}

// ---------------------------------------------------------------------------
// reduce 2 bf16 partials + bias -> Qbf/Kbf (bf16, pads zeroed) or Vf (fp32)
// grid (61, 3) x 128 threads
// ---------------------------------------------------------------------------
__global__ void reduce_qkv(const unsigned short* __restrict__ PQ,
                           const float* __restrict__ bq, const float* __restrict__ bk,
                           const float* __restrict__ bv,
                           unsigned short* __restrict__ Qbf,
                           unsigned short* __restrict__ Kbf,
                           float* __restrict__ Vf)
{
  const int mat = blockIdx.y;
  const int c = blockIdx.x * 128 + threadIdx.x;
  const float* bias = (mat == 0) ? bq : (mat == 1) ? bk : bv;
  const bool valid = c < DIN;
  const float bb = valid ? bias[c] : 0.f;
  const unsigned short* P0 = PQ + ((size_t)(mat * 2 + 0) * 256) * NPAD + c;
  const unsigned short* P1 = PQ + ((size_t)(mat * 2 + 1) * 256) * NPAD + c;
#pragma unroll 4
  for (int r = 0; r < 256; ++r) {
    float v = b2f(P0[(size_t)r * NPAD]) + b2f(P1[(size_t)r * NPAD]) + bb;
    if (!valid) v = 0.f;
    if (mat == 0)      Qbf[(size_t)r * KPAD + c] = (unsigned short)f2b(v);
    else if (mat == 1) Kbf[(size_t)r * KPAD + c] = (unsigned short)f2b(v);
    else               Vf[(size_t)r * NPAD + c] = v;
  }
}

// ---------------------------------------------------------------------------
// fused: sum 8 fp32 logit partials -> row softmax -> P (includes 1/256)
// grid 256 x 256 threads
// ---------------------------------------------------------------------------
__global__ void softmax_fused(const float* __restrict__ LP, float* __restrict__ P)
{
  __shared__ float red[8];
  const int m = blockIdx.x, t = threadIdx.x;
  float v = 0.f;
#pragma unroll
  for (int zz = 0; zz < 8; ++zz) v += LP[(size_t)zz * 65536 + m * 256 + t];
  const float scale = 1.0f / sqrtf((float)DIN);
  float mx = v;
#pragma unroll
  for (int o = 32; o >= 1; o >>= 1) mx = fmaxf(mx, __shfl_xor(mx, o, 64));
  if ((t & 63) == 0) red[t >> 6] = mx;
  __syncthreads();
  mx = fmaxf(fmaxf(red[0], red[1]), fmaxf(red[2], red[3]));
  float e = __expf((v - mx) * scale);
  float s = e;
#pragma unroll
  for (int o = 32; o >= 1; o >>= 1) s += __shfl_xor(s, o, 64);
  if ((t & 63) == 0) red[4 + (t >> 6)] = s;
  __syncthreads();
  s = red[4] + red[5] + red[6] + red[7];
  P[m * 256 + t] = e * (1.0f / 256.0f) / s;
}

// abar[n] = sum_m P[m][n]
__global__ void abar_kernel(const float* __restrict__ P, float* __restrict__ abar)
{
  const int n = threadIdx.x;
  float s = 0.f;
#pragma unroll 8
  for (int r = 0; r < 256; ++r) s += P[r * 256 + n];
  abar[n] = s;
}

// ctx[d] = sum_m abar[m] * V[m][d]
__global__ void ctx_kernel(const float* __restrict__ Vb, const float* __restrict__ abar,
                           float* __restrict__ ctx)
{
  __shared__ float ab[256];
  ab[threadIdx.x] = abar[threadIdx.x];
  __syncthreads();
  const int d = blockIdx.x * 256 + threadIdx.x;
  if (d >= DIN) return;
  float s = 0.f;
#pragma unroll 8
  for (int m = 0; m < 256; ++m) s += ab[m] * Vb[(size_t)m * NPAD + d];
  ctx[d] = s;
}

// base[j] += sum_{i in chunk} ctx[i] * (mu+sg*ep)[i][DIN+j]
__global__ void base_kernel(const float* __restrict__ mu, const float* __restrict__ sg,
                            const float* __restrict__ ep, const float* __restrict__ ctx,
                            float* __restrict__ base)
{
  const int j = threadIdx.x;
  if (j >= HOUT) return;
  const int i0 = blockIdx.x * 31;
  const int i1 = min(i0 + 31, DIN);
  float acc = 0.f;
#pragma unroll 4
  for (int i = i0; i < i1; ++i) {
    const size_t idx = (size_t)i * NNODE + DIN + j;
    acc = fmaf(ctx[i], fmaf(sg[idx], ep[idx], mu[idx]), acc);
  }
  atomicAdd(&base[j], acc);
}

// WsG[t][j] = (mu+sg*ep)[DIN+t][DIN+j]
__global__ void ws_kernel(const float* __restrict__ mu, const float* __restrict__ sg,
                          const float* __restrict__ ep, float* __restrict__ WsG)
{
  const int t = blockIdx.x;
  const int j = threadIdx.x;
  if (j >= HOUT) return;
  const size_t idx = (size_t)(DIN + t) * NNODE + DIN + j;
  WsG[t * HOUT + j] = fmaf(sg[idx], ep[idx], mu[idx]);
}

// sequential NEAT scan: 1 wave, acc in regs, rank-1 updates from LDS tiles
__global__ void scan_kernel(const float* __restrict__ WsG, const float* __restrict__ base,
                            const float* __restrict__ bmu, const float* __restrict__ bsg,
                            const float* __restrict__ epb, float* __restrict__ out)
{
  __shared__ float tile[32 * HOUT];
  const int l = threadIdx.x;
  float acc[5];
#pragma unroll
  for (int r = 0; r < 5; ++r) {
    int j = l + 64 * r;
    acc[r] = (j < HOUT) ? (base[j] + bmu[j] + bsg[j] * epb[j]) : 0.f;
  }
  for (int t0 = 0; t0 < HOUT; t0 += 32) {
    const int nrows = min(32, HOUT - t0);
    for (int r = 0; r < nrows; ++r)
      for (int c = l; c < HOUT; c += 64)
        tile[r * HOUT + c] = WsG[(t0 + r) * HOUT + c];
    __syncthreads();
    const int r2 = t0 >> 6;
    for (int tt = 0; tt < nrows; ++tt) {
      const int t = t0 + tt;
      float av = (r2 == 0) ? acc[0] : (r2 == 1) ? acc[1] :
                 (r2 == 2) ? acc[2] : (r2 == 3) ? acc[3] : acc[4];
      float pre = __shfl(av, t & 63, 64);
      float vt = tanhf(pre);
      if (t >= 256 && l == 0) out[t - 256] = vt;
#pragma unroll
      for (int r = 0; r < 5; ++r) {
        int j = l + 64 * r;
        if (j > t && j < HOUT) acc[r] += vt * tile[tt * HOUT + j];
      }
    }
    __syncthreads();
  }
}

// ---------------------------------------------------------------------------
extern "C" void kernel_launch(void* const* d_in, const int* in_sizes, int n_in,
                              void* d_out, int out_size, void* d_ws, size_t ws_size,
                              hipStream_t stream)
{
  const float* X   = (const float*)d_in[0];
  const float* Wq  = (const float*)d_in[1];
  const float* bq  = (const float*)d_in[2];
  const float* Wk  = (const float*)d_in[3];
  const float* bk  = (const float*)d_in[4];
  const float* Wv  = (const float*)d_in[5];
  const float* bv  = (const float*)d_in[6];
  const float* wmu = (const float*)d_in[7];
  const float* wsg = (const float*)d_in[8];
  const float* bmu = (const float*)d_in[9];
  const float* bsg = (const float*)d_in[10];
  const float* epw = (const float*)d_in[11];
  const float* epb = (const float*)d_in[12];

  char* p = (char*)d_ws;
  auto alloc = [&](size_t bytes) -> char* {
    char* r = p;
    p += (bytes + 255) & ~(size_t)255;
    return r;
  };
  unsigned short* Xb   = (unsigned short*)alloc((size_t)256 * KPAD * 2);
  unsigned short* PQKV = (unsigned short*)alloc((size_t)6 * 256 * NPAD * 2);
  unsigned short* Qbf  = (unsigned short*)alloc((size_t)256 * KPAD * 2);
  unsigned short* Kbf  = (unsigned short*)alloc((size_t)256 * KPAD * 2);
  float* Vf     = (float*)alloc((size_t)256 * NPAD * 4);
  float* LP     = (float*)alloc((size_t)8 * 65536 * 4);
  float* Pm     = (float*)alloc(65536 * 4);
  float* abar   = (float*)alloc(256 * 4);
  float* ctx    = (float*)alloc(7936 * 4);
  float* base   = (float*)alloc(HOUT * 4);
  float* WsG    = (float*)alloc(HOUT * HOUT * 4);

  prep_x<<<dim3(256), dim3(256), 0, stream>>>(X, Xb);
  hipMemsetAsync(base, 0, HOUT * 4, stream);

  // QKV: 122 col-tiles x 3 mats x 2 k-splits -> bf16 partials (no atomics)
  gemm_pipe<false><<<dim3(122, 3, 2), dim3(512), 0, stream>>>(
      Xb, KPAD, Wq, Wk, Wv,
      (long long)DIN * DIN - 4, DIN, DIN,
      (void*)PQKV, NPAD, 122);

  reduce_qkv<<<dim3(61, 3), dim3(128), 0, stream>>>(PQKV, bq, bk, bv, Qbf, Kbf, Vf);

  // logits: Q @ K^T, 4 col-tiles x 8 k-splits -> fp32 partials
  gemm_pipe<true><<<dim3(4, 1, 8), dim3(512), 0, stream>>>(
      Qbf, KPAD, Kbf, Kbf, Kbf,
      (long long)256 * KPAD - 4, KPAD, 256,
      (void*)LP, 256, 32);

  softmax_fused<<<dim3(256), dim3(256), 0, stream>>>(LP, Pm);
  abar_kernel<<<dim3(1), dim3(256), 0, stream>>>(Pm, abar);
  ctx_kernel<<<dim3(31), dim3(256), 0, stream>>>(Vf, abar, ctx);
  base_kernel<<<dim3(256), dim3(320), 0, stream>>>(wmu, wsg, epw, ctx, base);
  ws_kernel<<<dim3(260), dim3(320), 0, stream>>>(wmu, wsg, epw, WsG);
  scan_kernel<<<dim3(1), dim3(64), 0, stream>>>(WsG, base, bmu, bsg, epb, (float*)d_out);
}

// Round 4
// 939.973 us; speedup vs baseline: 1.0137x; 1.0137x over previous
//
#include <hip/hip_runtime.h>
#include <hip/hip_bf16.h>

#define DIN   7686
#define NNODE 7946
#define HOUT  260
#define KPAD2 8192   // k padded to 16*512
#define QK_STEPS 16  // 4096/256 per z-half

typedef __attribute__((ext_vector_type(8))) short bf16x8;
typedef __attribute__((ext_vector_type(4))) float f32x4;

__device__ __forceinline__ unsigned int f2b(float f) {
  union { float f; unsigned int u; } v; v.f = f;
  return (v.u + 0x7FFFu + ((v.u >> 16) & 1u)) >> 16;  // RNE float->bf16
}
__device__ __forceinline__ unsigned int pack2(float lo, float hi) {
  unsigned int r;
  asm("v_cvt_pk_bf16_f32 %0, %1, %2" : "=v"(r) : "v"(lo), "v"(hi));
  return r;
}
__device__ __forceinline__ float b2f(unsigned short h) {
  union { unsigned int u; float f; } v; v.u = ((unsigned int)h) << 16; return v.f;
}

// ---------------------------------------------------------------------------
// prep: fp32 X -> bf16, padded [256][KPAD2] with zeros beyond DIN
// ---------------------------------------------------------------------------
__global__ void prep_x(const float* __restrict__ X, unsigned short* __restrict__ Xb)
{
  const int mrow = blockIdx.x;
  for (int c = threadIdx.x; c < KPAD2; c += blockDim.x) {
    float v = (c < DIN) ? X[(size_t)mrow * DIN + c] : 0.f;
    Xb[(size_t)mrow * KPAD2 + c] = (unsigned short)f2b(v);
  }
}

// ---------------------------------------------------------------------------
// Q/K GEMM: P[m,n] = sum_k Xb[m,k]*W[n,k].  BM=256, BN=64, BK=256.
// B rows read as 1KB contiguous chunks per step (DRAM page locality).
// B reg-staged (float2, 8B-aligned), converted bf16 -> XOR-swizzled LDS dbuf.
// A read directly from global (L2-resident 4MB). Raw s_barrier (no vmcnt drain).
// grid (121, mat=2, z=2); bf16 partials (no atomics).
// ---------------------------------------------------------------------------
__global__ __launch_bounds__(512, 4)
void gemm_qk(const unsigned short* __restrict__ Xb,
             const float* __restrict__ Wq, const float* __restrict__ Wk,
             unsigned short* __restrict__ PQK)
{
  const int mat = blockIdx.y, z = blockIdx.z;
  const float* B = mat ? Wk : Wq;
  const int n0 = blockIdx.x * 64;
  const int tid = threadIdx.x, lane = tid & 63, wv = tid >> 6;
  const int wr = wv >> 1, wc = wv & 1;
  const int lm = lane & 15, lq = (lane >> 4) * 8;

  __shared__ __align__(16) unsigned short Bs[2][64 * 256];  // 32KB x2

  // staging: thread -> row r=tid>>3, seg sg=tid&7 (32 floats at sg*32)
  const int r = tid >> 3, sg = tid & 7;
  int bn = n0 + r; if (bn > DIN - 1) bn = DIN - 1;
  const long long bbase = (long long)bn * DIN + sg * 32;
  const int kBase = z * 4096;
  const long long bMax = (long long)DIN * DIN - 2;

  float2 ld[16];

  auto LOADB = [&](int kb) {
#pragma unroll
    for (int c = 0; c < 16; ++c) {
      long long idx = bbase + kBase + kb + c * 2;
      if (idx > bMax) idx = bMax;   // tail-safe; A pad zeros nullify
      ld[c] = *(const float2*)(B + idx);
    }
  };
  const int wbase = r * 512 + sg * 64;     // byte offset in tile
  const int wsw = (r & 7) << 4;            // T2 swizzle
  auto WRITEB = [&](int buf) {
    char* bs = (char*)Bs[buf];
#pragma unroll
    for (int c = 0; c < 4; ++c) {
      uint4 o;
      o.x = pack2(ld[4*c+0].x, ld[4*c+0].y);
      o.y = pack2(ld[4*c+1].x, ld[4*c+1].y);
      o.z = pack2(ld[4*c+2].x, ld[4*c+2].y);
      o.w = pack2(ld[4*c+3].x, ld[4*c+3].y);
      *(uint4*)(bs + (((wbase + c * 16)) ^ wsw)) = o;
    }
  };

  f32x4 acc[4][2] = {};

  auto COMPUTE = [&](int buf, int kb) {
    const char* bs = (const char*)Bs[buf];
#pragma unroll
    for (int ks = 0; ks < 8; ++ks) {
      bf16x8 bf[2];
#pragma unroll
      for (int j = 0; j < 2; ++j) {
        const int nl = wc * 32 + j * 16 + lm;
        const int rb = nl * 512 + ks * 64 + (lane >> 4) * 16;
        bf[j] = *(const bf16x8*)(bs + (rb ^ ((nl & 7) << 4)));
      }
      bf16x8 a[4];
#pragma unroll
      for (int i = 0; i < 4; ++i) {
        const int arow = wr * 64 + i * 16 + lm;
        a[i] = *(const bf16x8*)(Xb + (size_t)arow * KPAD2 + kBase + kb + ks * 32 + lq);
      }
#pragma unroll
      for (int i = 0; i < 4; ++i) {
        acc[i][0] = __builtin_amdgcn_mfma_f32_16x16x32_bf16(a[i], bf[0], acc[i][0], 0, 0, 0);
        acc[i][1] = __builtin_amdgcn_mfma_f32_16x16x32_bf16(a[i], bf[1], acc[i][1], 0, 0, 0);
      }
    }
  };

#define BAR() { asm volatile("s_waitcnt lgkmcnt(0)" ::: "memory"); \
                __builtin_amdgcn_s_barrier(); }

  LOADB(0);
  WRITEB(0);
  BAR();
  for (int s = 0; s < QK_STEPS; ++s) {
    if (s + 1 < QK_STEPS) LOADB((s + 1) * 256);   // issue early; in flight across barriers
    COMPUTE(s & 1, s * 256);
    BAR();
    if (s + 1 < QK_STEPS) WRITEB((s + 1) & 1);    // vmcnt waited here by reg dep
    BAR();
  }
#undef BAR

  unsigned short* Cp = PQK + (size_t)(mat * 2 + z) * 256 * KPAD2;
#pragma unroll
  for (int i = 0; i < 4; ++i) {
    const int r0 = wr * 64 + i * 16 + (lane >> 4) * 4;
#pragma unroll
    for (int j = 0; j < 2; ++j) {
      const int col = n0 + wc * 32 + j * 16 + lm;
#pragma unroll
      for (int q = 0; q < 4; ++q)
        Cp[(size_t)(r0 + q) * KPAD2 + col] = (unsigned short)f2b(acc[i][j][q]);
    }
  }
}

// ---------------------------------------------------------------------------
// reduce 2 bf16 partials + bias -> Qbf/Kbf bf16 [256][KPAD2], pads zeroed
// grid (64, 2) x 128 threads
// ---------------------------------------------------------------------------
__global__ void reduce_qk(const unsigned short* __restrict__ PQK,
                          const float* __restrict__ bq, const float* __restrict__ bk,
                          unsigned short* __restrict__ Qbf, unsigned short* __restrict__ Kbf)
{
  const int mat = blockIdx.y;
  const int c = blockIdx.x * 128 + threadIdx.x;
  const float* bias = mat ? bk : bq;
  const bool valid = c < DIN;
  const float bb = valid ? bias[c] : 0.f;
  const unsigned short* P0 = PQK + (size_t)(mat * 2 + 0) * 256 * KPAD2 + c;
  const unsigned short* P1 = PQK + (size_t)(mat * 2 + 1) * 256 * KPAD2 + c;
  unsigned short* O = (mat ? Kbf : Qbf) + c;
#pragma unroll 4
  for (int r = 0; r < 256; ++r) {
    float v = b2f(P0[(size_t)r * KPAD2]) + b2f(P1[(size_t)r * KPAD2]) + bb;
    if (!valid) v = 0.f;
    O[(size_t)r * KPAD2] = (unsigned short)f2b(v);
  }
}

// ---------------------------------------------------------------------------
// logits partials: LP[z][m][n] = sum_{k in chunk z} Q[m,k]*K[n,k]
// LDS-free: direct MFMA fragment loads from L2. grid (4,1,64) x 512.
// ---------------------------------------------------------------------------
__global__ __launch_bounds__(512)
void gemm_logits(const unsigned short* __restrict__ Qbf,
                 const unsigned short* __restrict__ Kbf, float* __restrict__ LP)
{
  const int qr = blockIdx.x & 1, qc = blockIdx.x >> 1, z = blockIdx.z;
  const int tid = threadIdx.x, lane = tid & 63, wv = tid >> 6;
  const int lm = lane & 15, lq = (lane >> 4) * 8;
  const int rowBase = qr * 128 + (wv & 3) * 32;
  const int colBase = qc * 128 + (wv >> 2) * 64;
  const int k0 = z * 128;
  f32x4 acc[2][4] = {};
#pragma unroll
  for (int ks = 0; ks < 4; ++ks) {
    bf16x8 a[2], b[4];
#pragma unroll
    for (int i = 0; i < 2; ++i)
      a[i] = *(const bf16x8*)(Qbf + (size_t)(rowBase + i * 16 + lm) * KPAD2 + k0 + ks * 32 + lq);
#pragma unroll
    for (int j = 0; j < 4; ++j)
      b[j] = *(const bf16x8*)(Kbf + (size_t)(colBase + j * 16 + lm) * KPAD2 + k0 + ks * 32 + lq);
#pragma unroll
    for (int i = 0; i < 2; ++i)
#pragma unroll
      for (int j = 0; j < 4; ++j)
        acc[i][j] = __builtin_amdgcn_mfma_f32_16x16x32_bf16(a[i], b[j], acc[i][j], 0, 0, 0);
  }
  float* out = LP + (size_t)z * 65536;
#pragma unroll
  for (int i = 0; i < 2; ++i) {
    const int r0 = rowBase + i * 16 + (lane >> 4) * 4;
#pragma unroll
    for (int j = 0; j < 4; ++j) {
      const int col = colBase + j * 16 + lm;
#pragma unroll
      for (int q = 0; q < 4; ++q)
        out[(size_t)(r0 + q) * 256 + col] = acc[i][j][q];
    }
  }
}

// ---------------------------------------------------------------------------
// fused: sum 64 fp32 logit partials -> row softmax -> P (includes 1/256)
// ---------------------------------------------------------------------------
__global__ void softmax_fused(const float* __restrict__ LP, float* __restrict__ P)
{
  __shared__ float red[8];
  const int m = blockIdx.x, t = threadIdx.x;
  float v = 0.f;
#pragma unroll 8
  for (int zz = 0; zz < 64; ++zz) v += LP[(size_t)zz * 65536 + m * 256 + t];
  const float scale = 1.0f / sqrtf((float)DIN);
  float mx = v;
#pragma unroll
  for (int o = 32; o >= 1; o >>= 1) mx = fmaxf(mx, __shfl_xor(mx, o, 64));
  if ((t & 63) == 0) red[t >> 6] = mx;
  __syncthreads();
  mx = fmaxf(fmaxf(red[0], red[1]), fmaxf(red[2], red[3]));
  float e = __expf((v - mx) * scale);
  float s = e;
#pragma unroll
  for (int o = 32; o >= 1; o >>= 1) s += __shfl_xor(s, o, 64);
  if ((t & 63) == 0) red[4 + (t >> 6)] = s;
  __syncthreads();
  s = red[4] + red[5] + red[6] + red[7];
  P[m * 256 + t] = e * (1.0f / 256.0f) / s;
}

// abar[n] = sum_m P[m][n]
__global__ void abar_kernel(const float* __restrict__ P, float* __restrict__ abar)
{
  const int n = threadIdx.x;
  float s = 0.f;
#pragma unroll 8
  for (int r = 0; r < 256; ++r) s += P[r * 256 + n];
  abar[n] = s;
}

// y[c] = sum_m abar[m] * X[m][c]  (fp32; padded to 7936 with zeros)
__global__ void y_kernel(const float* __restrict__ X, const float* __restrict__ abar,
                         float* __restrict__ y)
{
  __shared__ float ab[256];
  ab[threadIdx.x] = abar[threadIdx.x];
  __syncthreads();
  const int c = blockIdx.x * 256 + threadIdx.x;
  if (c >= 7936) return;
  float s = 0.f;
  if (c < DIN) {
#pragma unroll 8
    for (int m = 0; m < 256; ++m) s += ab[m] * X[(size_t)m * DIN + c];
  }
  y[c] = s;
}

// ctx[d] = Wv[d,:]·y + bv[d]   — pure sequential stream of Wv (236MB)
__global__ __launch_bounds__(256)
void ctx_mv(const float* __restrict__ Wv, const float* __restrict__ y,
            const float* __restrict__ bv, float* __restrict__ ctx)
{
  const int w = threadIdx.x >> 6, lane = threadIdx.x & 63;
  const int d = blockIdx.x * 4 + w;
  if (d >= DIN) return;
  const float* row = Wv + (size_t)d * DIN;
  float s = 0.f;
#pragma unroll 2
  for (int it = 0; it < 30; ++it) {   // 30*256 = 7680 floats
    const int k = it * 256 + lane * 4;
    float2 w0 = *(const float2*)(row + k);
    float2 w1 = *(const float2*)(row + k + 2);
    float2 y0 = *(const float2*)(y + k);
    float2 y1 = *(const float2*)(y + k + 2);
    s += w0.x * y0.x + w0.y * y0.y + w1.x * y1.x + w1.y * y1.y;
  }
  { // tail 7680..7685
    const int k = 7680 + lane;
    if (k < DIN) s += row[k] * y[k];
  }
#pragma unroll
  for (int o = 32; o >= 1; o >>= 1) s += __shfl_xor(s, o, 64);
  if (lane == 0) ctx[d] = s + bv[d];
}

// base[j] += sum_{i in chunk} ctx[i] * (mu+sg*ep)[i][DIN+j]
__global__ void base_kernel(const float* __restrict__ mu, const float* __restrict__ sg,
                            const float* __restrict__ ep, const float* __restrict__ ctx,
                            float* __restrict__ base)
{
  const int j = threadIdx.x;
  if (j >= HOUT) return;
  const int i0 = blockIdx.x * 31;
  const int i1 = min(i0 + 31, DIN);
  float acc = 0.f;
#pragma unroll 4
  for (int i = i0; i < i1; ++i) {
    const size_t idx = (size_t)i * NNODE + DIN + j;
    acc = fmaf(ctx[i], fmaf(sg[idx], ep[idx], mu[idx]), acc);
  }
  atomicAdd(&base[j], acc);
}

// WsG[t][j] = (mu+sg*ep)[DIN+t][DIN+j]
__global__ void ws_kernel(const float* __restrict__ mu, const float* __restrict__ sg,
                          const float* __restrict__ ep, float* __restrict__ WsG)
{
  const int t = blockIdx.x;
  const int j = threadIdx.x;
  if (j >= HOUT) return;
  const size_t idx = (size_t)(DIN + t) * NNODE + DIN + j;
  WsG[t * HOUT + j] = fmaf(sg[idx], ep[idx], mu[idx]);
}

// sequential NEAT scan: 1 wave, acc in regs, rank-1 updates from LDS tiles
__global__ void scan_kernel(const float* __restrict__ WsG, const float* __restrict__ base,
                            const float* __restrict__ bmu, const float* __restrict__ bsg,
                            const float* __restrict__ epb, float* __restrict__ out)
{
  __shared__ float tile[32 * HOUT];
  const int l = threadIdx.x;
  float acc[5];
#pragma unroll
  for (int r = 0; r < 5; ++r) {
    int j = l + 64 * r;
    acc[r] = (j < HOUT) ? (base[j] + bmu[j] + bsg[j] * epb[j]) : 0.f;
  }
  for (int t0 = 0; t0 < HOUT; t0 += 32) {
    const int nrows = min(32, HOUT - t0);
    for (int r = 0; r < nrows; ++r)
      for (int c = l; c < HOUT; c += 64)
        tile[r * HOUT + c] = WsG[(t0 + r) * HOUT + c];
    __syncthreads();
    const int r2 = t0 >> 6;
    for (int tt = 0; tt < nrows; ++tt) {
      const int t = t0 + tt;
      float av = (r2 == 0) ? acc[0] : (r2 == 1) ? acc[1] :
                 (r2 == 2) ? acc[2] : (r2 == 3) ? acc[3] : acc[4];
      float pre = __shfl(av, t & 63, 64);
      float vt = tanhf(pre);
      if (t >= 256 && l == 0) out[t - 256] = vt;
#pragma unroll
      for (int r = 0; r < 5; ++r) {
        int j = l + 64 * r;
        if (j > t && j < HOUT) acc[r] += vt * tile[tt * HOUT + j];
      }
    }
    __syncthreads();
  }
}

// ---------------------------------------------------------------------------
extern "C" void kernel_launch(void* const* d_in, const int* in_sizes, int n_in,
                              void* d_out, int out_size, void* d_ws, size_t ws_size,
                              hipStream_t stream)
{
  const float* X   = (const float*)d_in[0];
  const float* Wq  = (const float*)d_in[1];
  const float* bq  = (const float*)d_in[2];
  const float* Wk  = (const float*)d_in[3];
  const float* bk  = (const float*)d_in[4];
  const float* Wv  = (const float*)d_in[5];
  const float* bv  = (const float*)d_in[6];
  const float* wmu = (const float*)d_in[7];
  const float* wsg = (const float*)d_in[8];
  const float* bmu = (const float*)d_in[9];
  const float* bsg = (const float*)d_in[10];
  const float* epw = (const float*)d_in[11];
  const float* epb = (const float*)d_in[12];

  char* p = (char*)d_ws;
  auto alloc = [&](size_t bytes) -> char* {
    char* r = p;
    p += (bytes + 255) & ~(size_t)255;
    return r;
  };
  unsigned short* Xb  = (unsigned short*)alloc((size_t)256 * KPAD2 * 2);
  unsigned short* PQK = (unsigned short*)alloc((size_t)4 * 256 * KPAD2 * 2);
  unsigned short* Qbf = (unsigned short*)alloc((size_t)256 * KPAD2 * 2);
  unsigned short* Kbf = (unsigned short*)alloc((size_t)256 * KPAD2 * 2);
  float* LP   = (float*)alloc((size_t)64 * 65536 * 4);
  float* Pm   = (float*)alloc(65536 * 4);
  float* abar = (float*)alloc(256 * 4);
  float* y    = (float*)alloc(7936 * 4);
  float* ctx  = (float*)alloc(7686 * 4);
  float* base = (float*)alloc(HOUT * 4);
  float* WsG  = (float*)alloc(HOUT * HOUT * 4);

  prep_x<<<dim3(256), dim3(256), 0, stream>>>(X, Xb);
  hipMemsetAsync(base, 0, HOUT * 4, stream);

  gemm_qk<<<dim3(121, 2, 2), dim3(512), 0, stream>>>(Xb, Wq, Wk, PQK);
  reduce_qk<<<dim3(64, 2), dim3(128), 0, stream>>>(PQK, bq, bk, Qbf, Kbf);
  gemm_logits<<<dim3(4, 1, 64), dim3(512), 0, stream>>>(Qbf, Kbf, LP);
  softmax_fused<<<dim3(256), dim3(256), 0, stream>>>(LP, Pm);
  abar_kernel<<<dim3(1), dim3(256), 0, stream>>>(Pm, abar);
  y_kernel<<<dim3(31), dim3(256), 0, stream>>>(X, abar, y);
  ctx_mv<<<dim3(1922), dim3(256), 0, stream>>>(Wv, y, bv, ctx);
  base_kernel<<<dim3(256), dim3(320), 0, stream>>>(wmu, wsg, epw, ctx, base);
  ws_kernel<<<dim3(260), dim3(320), 0, stream>>>(wmu, wsg, epw, WsG);
  scan_kernel<<<dim3(1), dim3(64), 0, stream>>>(WsG, base, bmu, bsg, epb, (float*)d_out);
}

// Round 5
// 695.036 us; speedup vs baseline: 1.3709x; 1.3524x over previous
//
#include <hip/hip_runtime.h>
#include <hip/hip_bf16.h>

#define DIN   7686
#define NNODE 7946
#define HOUT  260
#define KP    8192   // padded k (64 tiles of 128)

typedef __attribute__((ext_vector_type(8))) short bf16x8;
typedef __attribute__((ext_vector_type(4))) float f32x4;

__device__ __forceinline__ unsigned int f2b(float f) {
  union { float f; unsigned int u; } v; v.f = f;
  return (v.u + 0x7FFFu + ((v.u >> 16) & 1u)) >> 16;  // RNE float->bf16
}
__device__ __forceinline__ unsigned int pack2(float lo, float hi) {
  unsigned int r;
  asm("v_cvt_pk_bf16_f32 %0, %1, %2" : "=v"(r) : "v"(lo), "v"(hi));
  return r;
}
__device__ __forceinline__ float b2f(unsigned short h) {
  union { unsigned int u; float f; } v; v.u = ((unsigned int)h) << 16; return v.f;
}
__device__ __forceinline__ void gload16(const void* g, void* l) {
  __builtin_amdgcn_global_load_lds(
      (const __attribute__((address_space(1))) unsigned int*)g,
      (__attribute__((address_space(3))) unsigned int*)l, 16, 0, 0);
}

// ---------------------------------------------------------------------------
// prep: fp32 X -> bf16, tiled+swizzled: tile kc (64KB) holds [m=256][k=128],
// byte addr = kc*65536 + m*256 + (((k&127)*2) ^ ((m&7)<<4)).  Pads zeroed.
// ---------------------------------------------------------------------------
__global__ void prep_x(const float* __restrict__ X, unsigned short* __restrict__ XbT)
{
  const int m = blockIdx.x, t = threadIdx.x;
  const float* row = X + (size_t)m * DIN;
#pragma unroll
  for (int c2 = 0; c2 < 4; ++c2) {
    const int k8 = (c2 * 256 + t) * 8;
    float f[8];
    if (k8 + 8 <= DIN) {
#pragma unroll
      for (int h = 0; h < 4; ++h) {
        float2 v = *(const float2*)(row + k8 + h * 2);
        f[h * 2] = v.x; f[h * 2 + 1] = v.y;
      }
    } else {
#pragma unroll
      for (int h = 0; h < 8; ++h) f[h] = (k8 + h < DIN) ? row[k8 + h] : 0.f;
    }
    uint4 o;
    o.x = pack2(f[0], f[1]); o.y = pack2(f[2], f[3]);
    o.z = pack2(f[4], f[5]); o.w = pack2(f[6], f[7]);
    const int kc = k8 >> 7;
    char* dst = (char*)XbT + (size_t)kc * 65536 + m * 256 +
                (((k8 & 127) * 2) ^ ((m & 7) << 4));
    *(uint4*)dst = o;
  }
}

// ---------------------------------------------------------------------------
// Q/K GEMM, full-K per WG: Out[m][n] = sum_k X[m,k]*W[n,k] + bias[n] (bf16)
// BM=256, BN=64, BK=128, 64 steps. 512 thr = 8 waves (4 row x 2 col).
// B: one W row per wave-instr (64 lanes x float2 = 512B contiguous run),
//    fp32->bf16 -> XOR-swizzled LDS (16KB single buffer).
// A: global_load_lds from pre-swizzled XbT tiles (2x64KB double buffer).
// Counted vmcnt(8)/vmcnt(16): one step of prefetch always in flight.
// ---------------------------------------------------------------------------
__global__ __launch_bounds__(512)
void gemm_qk2(const unsigned short* __restrict__ XbT,
              const float* __restrict__ Wq, const float* __restrict__ Wk,
              const float* __restrict__ bq, const float* __restrict__ bk,
              unsigned short* __restrict__ Qbf, unsigned short* __restrict__ Kbf)
{
  const int mat = blockIdx.y;
  const float* W = mat ? Wk : Wq;
  const float* bias = mat ? bk : bq;
  unsigned short* Out = mat ? Kbf : Qbf;
  const int nt = blockIdx.x, n0 = nt * 64;
  const int tid = threadIdx.x, l = tid & 63, wv = tid >> 6;
  const int wr = wv >> 1, wc = wv & 1;
  const int lm = l & 15;

  __shared__ __align__(16) unsigned short As[2][32768];  // 2 x 64KB
  __shared__ __align__(16) unsigned short Bs[8192];      // 16KB

  // clamped global row bases for this wave's 8 B-rows
  long long wrb[8];
#pragma unroll
  for (int r = 0; r < 8; ++r) {
    int rg = n0 + wv * 8 + r;
    if (rg > DIN - 1) rg = DIN - 1;
    wrb[r] = (long long)rg * DIN;
  }

  float2 breg[8];
  auto RLOADB = [&](int s) {
    const int ss = (s < 64) ? s : 63;
    const int kk = ss * 128 + l * 2;
    const int kcl = (kk < DIN) ? kk : 0;
    const bool ok = kk < DIN;
#pragma unroll
    for (int r = 0; r < 8; ++r) {
      float2 v = *(const float2*)(W + wrb[r] + kcl);
      if (!ok) { v.x = 0.f; v.y = 0.f; }
      breg[r] = v;
    }
  };
  auto SWRITE = [&]() {
#pragma unroll
    for (int r = 0; r < 8; ++r) {
      const int lrow = wv * 8 + r;
      const int off = lrow * 256 + ((l * 4) ^ ((r & 7) << 4));
      *(unsigned int*)((char*)Bs + off) = pack2(breg[r].x, breg[r].y);
    }
  };
  auto GLOADA = [&](int s, int buf) {
    const int kc = (s < 64) ? s : 63;
    const char* g = (const char*)XbT + (size_t)kc * 65536;
    char* lb = (char*)&As[buf][0];
#pragma unroll
    for (int q = 0; q < 8; ++q) {
      const int chunk = q * 8 + wv;
      gload16(g + chunk * 1024 + l * 16, lb + chunk * 1024);
    }
  };

  f32x4 acc[4][2] = {};
  const int sw = (l & 7) << 4;
  const int lq16 = ((l >> 4) & 3) * 16;

  auto COMPUTE = [&](int buf) {
    const char* a_ = (const char*)&As[buf][0];
    const char* b_ = (const char*)Bs;
#pragma unroll
    for (int ks = 0; ks < 4; ++ks) {
      bf16x8 bf[2];
#pragma unroll
      for (int j = 0; j < 2; ++j) {
        const int n = wc * 32 + j * 16 + lm;
        bf[j] = *(const bf16x8*)(b_ + n * 256 + ((ks * 64 + lq16) ^ sw));
      }
#pragma unroll
      for (int i = 0; i < 4; ++i) {
        const int m = wr * 64 + i * 16 + lm;
        bf16x8 a = *(const bf16x8*)(a_ + m * 256 + ((ks * 64 + lq16) ^ sw));
        acc[i][0] = __builtin_amdgcn_mfma_f32_16x16x32_bf16(a, bf[0], acc[i][0], 0, 0, 0);
        acc[i][1] = __builtin_amdgcn_mfma_f32_16x16x32_bf16(a, bf[1], acc[i][1], 0, 0, 0);
      }
    }
  };

#define WAITV(n) { asm volatile("s_waitcnt vmcnt(" #n ")" ::: "memory"); \
                   __builtin_amdgcn_sched_barrier(0); }
#define WAITL    { asm volatile("s_waitcnt lgkmcnt(0)" ::: "memory"); \
                   __builtin_amdgcn_sched_barrier(0); }

  // prologue: stage B(0), A(0); leave B(1)+A(1) in flight (16 outstanding)
  RLOADB(0); GLOADA(0, 0);
  WAITV(0)
  SWRITE();
  RLOADB(1); GLOADA(1, 1);
  WAITL
  __builtin_amdgcn_s_barrier();

  for (int s = 0; s < 64; ++s) {
    COMPUTE(s & 1);
    if (s == 63) break;
    WAITV(8)                      // B(s+1) regs ready; A(s+1) still flying
    __builtin_amdgcn_s_barrier(); // all waves done reading Bs / As[s&1]
    SWRITE();                     // Bs <- B(s+1)
    RLOADB(s + 2);                // 8 issues (clamped past end)
    GLOADA(s + 2, s & 1);         // 8 issues into freed A buffer
    WAITL
    WAITV(16)                     // A(s+1) landed; B(s+2)+A(s+2) in flight
    __builtin_amdgcn_s_barrier();
  }
#undef WAITV
#undef WAITL

  // epilogue: Out[m][col] = acc + bias (bf16); col >= DIN -> 0
#pragma unroll
  for (int i = 0; i < 4; ++i) {
    const int r0 = wr * 64 + i * 16 + (l >> 4) * 4;
#pragma unroll
    for (int j = 0; j < 2; ++j) {
      const int col = n0 + wc * 32 + j * 16 + lm;
      const float bb = (col < DIN) ? bias[col] : 0.f;
#pragma unroll
      for (int q = 0; q < 4; ++q) {
        const float v = acc[i][j][q] + bb;
        Out[(size_t)(r0 + q) * KP + col] = (col < DIN) ? (unsigned short)f2b(v) : 0;
      }
    }
  }
}

// ---------------------------------------------------------------------------
// logits partials: LP[z][m][n] = sum_{k in chunk z} Q[m,k]*K[n,k]
// LDS-free, L2-resident inputs. grid (4,1,64) x 512.
// ---------------------------------------------------------------------------
__global__ __launch_bounds__(512)
void gemm_logits(const unsigned short* __restrict__ Qbf,
                 const unsigned short* __restrict__ Kbf, float* __restrict__ LP)
{
  const int qr = blockIdx.x & 1, qc = blockIdx.x >> 1, z = blockIdx.z;
  const int tid = threadIdx.x, lane = tid & 63, wv = tid >> 6;
  const int lm = lane & 15, lq = (lane >> 4) * 8;
  const int rowBase = qr * 128 + (wv & 3) * 32;
  const int colBase = qc * 128 + (wv >> 2) * 64;
  const int k0 = z * 128;
  f32x4 acc[2][4] = {};
#pragma unroll
  for (int ks = 0; ks < 4; ++ks) {
    bf16x8 a[2], b[4];
#pragma unroll
    for (int i = 0; i < 2; ++i)
      a[i] = *(const bf16x8*)(Qbf + (size_t)(rowBase + i * 16 + lm) * KP + k0 + ks * 32 + lq);
#pragma unroll
    for (int j = 0; j < 4; ++j)
      b[j] = *(const bf16x8*)(Kbf + (size_t)(colBase + j * 16 + lm) * KP + k0 + ks * 32 + lq);
#pragma unroll
    for (int i = 0; i < 2; ++i)
#pragma unroll
      for (int j = 0; j < 4; ++j)
        acc[i][j] = __builtin_amdgcn_mfma_f32_16x16x32_bf16(a[i], b[j], acc[i][j], 0, 0, 0);
  }
  float* out = LP + (size_t)z * 65536;
#pragma unroll
  for (int i = 0; i < 2; ++i) {
    const int r0 = rowBase + i * 16 + (lane >> 4) * 4;
#pragma unroll
    for (int j = 0; j < 4; ++j) {
      const int col = colBase + j * 16 + lm;
#pragma unroll
      for (int q = 0; q < 4; ++q)
        out[(size_t)(r0 + q) * 256 + col] = acc[i][j][q];
    }
  }
}

// ---------------------------------------------------------------------------
// fused: sum 64 logit partials -> row softmax -> atomicAdd into abar (w/ 1/256)
// ---------------------------------------------------------------------------
__global__ void softmax_fused(const float* __restrict__ LP, float* __restrict__ abar)
{
  __shared__ float red[8];
  const int m = blockIdx.x, t = threadIdx.x;
  float v = 0.f;
#pragma unroll 8
  for (int zz = 0; zz < 64; ++zz) v += LP[(size_t)zz * 65536 + m * 256 + t];
  const float scale = 1.0f / sqrtf((float)DIN);
  float mx = v;
#pragma unroll
  for (int o = 32; o >= 1; o >>= 1) mx = fmaxf(mx, __shfl_xor(mx, o, 64));
  if ((t & 63) == 0) red[t >> 6] = mx;
  __syncthreads();
  mx = fmaxf(fmaxf(red[0], red[1]), fmaxf(red[2], red[3]));
  float e = __expf((v - mx) * scale);
  float s = e;
#pragma unroll
  for (int o = 32; o >= 1; o >>= 1) s += __shfl_xor(s, o, 64);
  if ((t & 63) == 0) red[4 + (t >> 6)] = s;
  __syncthreads();
  s = red[4] + red[5] + red[6] + red[7];
  atomicAdd(&abar[t], e * (1.0f / 256.0f) / s);
}

// y[c] = sum_m abar[m] * X[m][c]
__global__ void y_kernel(const float* __restrict__ X, const float* __restrict__ abar,
                         float* __restrict__ y)
{
  __shared__ float ab[256];
  ab[threadIdx.x] = abar[threadIdx.x];
  __syncthreads();
  const int c = blockIdx.x * 256 + threadIdx.x;
  if (c >= DIN) return;
  float s = 0.f;
#pragma unroll 8
  for (int m = 0; m < 256; ++m) s += ab[m] * X[(size_t)m * DIN + c];
  y[c] = s;
}

// ctx[d] = Wv[d,:]·y + bv[d] — one row per wave, lane-contiguous float2 stream
__global__ __launch_bounds__(512)
void ctx_mv(const float* __restrict__ Wv, const float* __restrict__ y,
            const float* __restrict__ bv, float* __restrict__ ctx)
{
  const int wv = threadIdx.x >> 6, l = threadIdx.x & 63;
  const int row = blockIdx.x * 8 + wv;
  if (row >= DIN) return;
  const float* wr_ = Wv + (size_t)row * DIN;
  float s = 0.f;
  for (int it = 0; it < 61; ++it) {
    const int k = it * 128 + l * 2;
    if (k < DIN) {
      float2 w2 = *(const float2*)(wr_ + k);
      float2 y2 = *(const float2*)(y + k);
      s = fmaf(w2.x, y2.x, s);
      s = fmaf(w2.y, y2.y, s);
    }
  }
#pragma unroll
  for (int o = 32; o >= 1; o >>= 1) s += __shfl_xor(s, o, 64);
  if (l == 0) ctx[row] = s + bv[row];
}

// base[j] += sum_{i in chunk} ctx[i] * (mu+sg*ep)[i][DIN+j]
__global__ void base_kernel(const float* __restrict__ mu, const float* __restrict__ sg,
                            const float* __restrict__ ep, const float* __restrict__ ctx,
                            float* __restrict__ base)
{
  const int j = threadIdx.x;
  if (j >= HOUT) return;
  const int i0 = blockIdx.x * 31;
  const int i1 = min(i0 + 31, DIN);
  float acc = 0.f;
#pragma unroll 4
  for (int i = i0; i < i1; ++i) {
    const size_t idx = (size_t)i * NNODE + DIN + j;
    acc = fmaf(ctx[i], fmaf(sg[idx], ep[idx], mu[idx]), acc);
  }
  atomicAdd(&base[j], acc);
}

// WsG[t][j] = (mu+sg*ep)[DIN+t][DIN+j]
__global__ void ws_kernel(const float* __restrict__ mu, const float* __restrict__ sg,
                          const float* __restrict__ ep, float* __restrict__ WsG)
{
  const int t = blockIdx.x;
  const int j = threadIdx.x;
  if (j >= HOUT) return;
  const size_t idx = (size_t)(DIN + t) * NNODE + DIN + j;
  WsG[t * HOUT + j] = fmaf(sg[idx], ep[idx], mu[idx]);
}

// sequential NEAT scan: 1 wave, acc in regs, rank-1 updates from LDS tiles
__global__ void scan_kernel(const float* __restrict__ WsG, const float* __restrict__ base,
                            const float* __restrict__ bmu, const float* __restrict__ bsg,
                            const float* __restrict__ epb, float* __restrict__ out)
{
  __shared__ float tile[32 * HOUT];
  const int l = threadIdx.x;
  float acc[5];
#pragma unroll
  for (int r = 0; r < 5; ++r) {
    int j = l + 64 * r;
    acc[r] = (j < HOUT) ? (base[j] + bmu[j] + bsg[j] * epb[j]) : 0.f;
  }
  for (int t0 = 0; t0 < HOUT; t0 += 32) {
    const int nrows = min(32, HOUT - t0);
    for (int r = 0; r < nrows; ++r)
      for (int c = l; c < HOUT; c += 64)
        tile[r * HOUT + c] = WsG[(t0 + r) * HOUT + c];
    __syncthreads();
    const int r2 = t0 >> 6;
    for (int tt = 0; tt < nrows; ++tt) {
      const int t = t0 + tt;
      float av = (r2 == 0) ? acc[0] : (r2 == 1) ? acc[1] :
                 (r2 == 2) ? acc[2] : (r2 == 3) ? acc[3] : acc[4];
      float pre = __shfl(av, t & 63, 64);
      float vt = tanhf(pre);
      if (t >= 256 && l == 0) out[t - 256] = vt;
#pragma unroll
      for (int r = 0; r < 5; ++r) {
        int j = l + 64 * r;
        if (j > t && j < HOUT) acc[r] += vt * tile[tt * HOUT + j];
      }
    }
    __syncthreads();
  }
}

// ---------------------------------------------------------------------------
extern "C" void kernel_launch(void* const* d_in, const int* in_sizes, int n_in,
                              void* d_out, int out_size, void* d_ws, size_t ws_size,
                              hipStream_t stream)
{
  const float* X   = (const float*)d_in[0];
  const float* Wq  = (const float*)d_in[1];
  const float* bq  = (const float*)d_in[2];
  const float* Wk  = (const float*)d_in[3];
  const float* bk  = (const float*)d_in[4];
  const float* Wv  = (const float*)d_in[5];
  const float* bv  = (const float*)d_in[6];
  const float* wmu = (const float*)d_in[7];
  const float* wsg = (const float*)d_in[8];
  const float* bmu = (const float*)d_in[9];
  const float* bsg = (const float*)d_in[10];
  const float* epw = (const float*)d_in[11];
  const float* epb = (const float*)d_in[12];

  char* p = (char*)d_ws;
  auto alloc = [&](size_t bytes) -> char* {
    char* r = p;
    p += (bytes + 255) & ~(size_t)255;
    return r;
  };
  unsigned short* XbT = (unsigned short*)alloc((size_t)64 * 65536);        // 4MB
  unsigned short* Qbf = (unsigned short*)alloc((size_t)256 * KP * 2);      // 4MB
  unsigned short* Kbf = (unsigned short*)alloc((size_t)256 * KP * 2);      // 4MB
  float* LP   = (float*)alloc((size_t)64 * 65536 * 4);                     // 16MB
  float* abar = (float*)alloc(256 * 4);
  float* y    = (float*)alloc(7686 * 4);
  float* ctx  = (float*)alloc(7686 * 4);
  float* base = (float*)alloc(HOUT * 4);
  float* WsG  = (float*)alloc(HOUT * HOUT * 4);

  prep_x<<<dim3(256), dim3(256), 0, stream>>>(X, XbT);
  hipMemsetAsync(abar, 0, 256 * 4, stream);
  hipMemsetAsync(base, 0, HOUT * 4, stream);
  hipMemsetAsync(Qbf, 0, (size_t)256 * KP * 2, stream);
  hipMemsetAsync(Kbf, 0, (size_t)256 * KP * 2, stream);

  gemm_qk2<<<dim3(121, 2), dim3(512), 0, stream>>>(XbT, Wq, Wk, bq, bk, Qbf, Kbf);
  gemm_logits<<<dim3(4, 1, 64), dim3(512), 0, stream>>>(Qbf, Kbf, LP);
  softmax_fused<<<dim3(256), dim3(256), 0, stream>>>(LP, abar);
  y_kernel<<<dim3(31), dim3(256), 0, stream>>>(X, abar, y);
  ctx_mv<<<dim3(961), dim3(512), 0, stream>>>(Wv, y, bv, ctx);
  base_kernel<<<dim3(256), dim3(320), 0, stream>>>(wmu, wsg, epw, ctx, base);
  ws_kernel<<<dim3(260), dim3(320), 0, stream>>>(wmu, wsg, epw, WsG);
  scan_kernel<<<dim3(1), dim3(64), 0, stream>>>(WsG, base, bmu, bsg, epb, (float*)d_out);
}

// Round 6
// 405.683 us; speedup vs baseline: 2.3487x; 1.7132x over previous
//
#include <hip/hip_runtime.h>
#include <hip/hip_bf16.h>
#include <type_traits>

#define DIN   7686
#define NNODE 7946
#define HOUT  260
#define KP    8192   // padded k (64 tiles of 128)

typedef __attribute__((ext_vector_type(8))) short bf16x8;
typedef __attribute__((ext_vector_type(4))) float f32x4;

__device__ __forceinline__ unsigned int f2b(float f) {
  union { float f; unsigned int u; } v; v.f = f;
  return (v.u + 0x7FFFu + ((v.u >> 16) & 1u)) >> 16;  // RNE float->bf16
}
__device__ __forceinline__ unsigned int pack2(float lo, float hi) {
  unsigned int r;
  asm("v_cvt_pk_bf16_f32 %0, %1, %2" : "=v"(r) : "v"(lo), "v"(hi));
  return r;
}
__device__ __forceinline__ float b2f(unsigned short h) {
  union { unsigned int u; float f; } v; v.u = ((unsigned int)h) << 16; return v.f;
}
__device__ __forceinline__ void gload16(const void* g, void* l) {
  __builtin_amdgcn_global_load_lds(
      (const __attribute__((address_space(1))) unsigned int*)g,
      (__attribute__((address_space(3))) unsigned int*)l, 16, 0, 0);
}
__device__ __forceinline__ float readlane_f(float v, int lane) {
  return __uint_as_float(__builtin_amdgcn_readlane(__float_as_uint(v), lane));
}

// ---------------------------------------------------------------------------
// prep: fp32 X -> bf16, tiled+swizzled: tile kc (64KB) holds [m=256][k=128],
// byte addr = kc*65536 + m*256 + (((k&127)*2) ^ ((m&7)<<4)).  Pads zeroed.
// ---------------------------------------------------------------------------
__global__ void prep_x(const float* __restrict__ X, unsigned short* __restrict__ XbT)
{
  const int m = blockIdx.x, t = threadIdx.x;
  const float* row = X + (size_t)m * DIN;
#pragma unroll
  for (int c2 = 0; c2 < 4; ++c2) {
    const int k8 = (c2 * 256 + t) * 8;
    float f[8];
    if (k8 + 8 <= DIN) {
#pragma unroll
      for (int h = 0; h < 4; ++h) {
        float2 v = *(const float2*)(row + k8 + h * 2);
        f[h * 2] = v.x; f[h * 2 + 1] = v.y;
      }
    } else {
#pragma unroll
      for (int h = 0; h < 8; ++h) f[h] = (k8 + h < DIN) ? row[k8 + h] : 0.f;
    }
    uint4 o;
    o.x = pack2(f[0], f[1]); o.y = pack2(f[2], f[3]);
    o.z = pack2(f[4], f[5]); o.w = pack2(f[6], f[7]);
    const int kc = k8 >> 7;
    char* dst = (char*)XbT + (size_t)kc * 65536 + m * 256 +
                (((k8 & 127) * 2) ^ ((m & 7) << 4));
    *(uint4*)dst = o;
  }
}

// ---------------------------------------------------------------------------
// Q/K GEMM, full-K per WG: Out[m][n] = sum_k X[m,k]*W[n,k] + bias[n] (bf16)
// BM=256, BN=64, BK=128, 64 steps. 512 thr = 8 waves (4 row x 2 col).
// ---------------------------------------------------------------------------
__global__ __launch_bounds__(512)
void gemm_qk2(const unsigned short* __restrict__ XbT,
              const float* __restrict__ Wq, const float* __restrict__ Wk,
              const float* __restrict__ bq, const float* __restrict__ bk,
              unsigned short* __restrict__ Qbf, unsigned short* __restrict__ Kbf)
{
  const int mat = blockIdx.y;
  const float* W = mat ? Wk : Wq;
  const float* bias = mat ? bk : bq;
  unsigned short* Out = mat ? Kbf : Qbf;
  const int nt = blockIdx.x, n0 = nt * 64;
  const int tid = threadIdx.x, l = tid & 63, wv = tid >> 6;
  const int wr = wv >> 1, wc = wv & 1;
  const int lm = l & 15;

  __shared__ __align__(16) unsigned short As[2][32768];  // 2 x 64KB
  __shared__ __align__(16) unsigned short Bs[8192];      // 16KB

  long long wrb[8];
#pragma unroll
  for (int r = 0; r < 8; ++r) {
    int rg = n0 + wv * 8 + r;
    if (rg > DIN - 1) rg = DIN - 1;
    wrb[r] = (long long)rg * DIN;
  }

  float2 breg[8];
  auto RLOADB = [&](int s) {
    const int ss = (s < 64) ? s : 63;
    const int kk = ss * 128 + l * 2;
    const int kcl = (kk < DIN) ? kk : 0;
    const bool ok = kk < DIN;
#pragma unroll
    for (int r = 0; r < 8; ++r) {
      float2 v = *(const float2*)(W + wrb[r] + kcl);
      if (!ok) { v.x = 0.f; v.y = 0.f; }
      breg[r] = v;
    }
  };
  auto SWRITE = [&]() {
#pragma unroll
    for (int r = 0; r < 8; ++r) {
      const int lrow = wv * 8 + r;
      const int off = lrow * 256 + ((l * 4) ^ ((r & 7) << 4));
      *(unsigned int*)((char*)Bs + off) = pack2(breg[r].x, breg[r].y);
    }
  };
  auto GLOADA = [&](int s, int buf) {
    const int kc = (s < 64) ? s : 63;
    const char* g = (const char*)XbT + (size_t)kc * 65536;
    char* lb = (char*)&As[buf][0];
#pragma unroll
    for (int q = 0; q < 8; ++q) {
      const int chunk = q * 8 + wv;
      gload16(g + chunk * 1024 + l * 16, lb + chunk * 1024);
    }
  };

  f32x4 acc[4][2] = {};
  const int sw = (l & 7) << 4;
  const int lq16 = ((l >> 4) & 3) * 16;

  auto COMPUTE = [&](int buf) {
    const char* a_ = (const char*)&As[buf][0];
    const char* b_ = (const char*)Bs;
#pragma unroll
    for (int ks = 0; ks < 4; ++ks) {
      bf16x8 bf[2];
#pragma unroll
      for (int j = 0; j < 2; ++j) {
        const int n = wc * 32 + j * 16 + lm;
        bf[j] = *(const bf16x8*)(b_ + n * 256 + ((ks * 64 + lq16) ^ sw));
      }
#pragma unroll
      for (int i = 0; i < 4; ++i) {
        const int m = wr * 64 + i * 16 + lm;
        bf16x8 a = *(const bf16x8*)(a_ + m * 256 + ((ks * 64 + lq16) ^ sw));
        acc[i][0] = __builtin_amdgcn_mfma_f32_16x16x32_bf16(a, bf[0], acc[i][0], 0, 0, 0);
        acc[i][1] = __builtin_amdgcn_mfma_f32_16x16x32_bf16(a, bf[1], acc[i][1], 0, 0, 0);
      }
    }
  };

#define WAITV(n) { asm volatile("s_waitcnt vmcnt(" #n ")" ::: "memory"); \
                   __builtin_amdgcn_sched_barrier(0); }
#define WAITL    { asm volatile("s_waitcnt lgkmcnt(0)" ::: "memory"); \
                   __builtin_amdgcn_sched_barrier(0); }

  RLOADB(0); GLOADA(0, 0);
  WAITV(0)
  SWRITE();
  RLOADB(1); GLOADA(1, 1);
  WAITL
  __builtin_amdgcn_s_barrier();

  for (int s = 0; s < 64; ++s) {
    COMPUTE(s & 1);
    if (s == 63) break;
    WAITV(8)
    __builtin_amdgcn_s_barrier();
    SWRITE();
    RLOADB(s + 2);
    GLOADA(s + 2, s & 1);
    WAITL
    WAITV(16)
    __builtin_amdgcn_s_barrier();
  }
#undef WAITV
#undef WAITL

#pragma unroll
  for (int i = 0; i < 4; ++i) {
    const int r0 = wr * 64 + i * 16 + (l >> 4) * 4;
#pragma unroll
    for (int j = 0; j < 2; ++j) {
      const int col = n0 + wc * 32 + j * 16 + lm;
      const float bb = (col < DIN) ? bias[col] : 0.f;
#pragma unroll
      for (int q = 0; q < 4; ++q) {
        const float v = acc[i][j][q] + bb;
        Out[(size_t)(r0 + q) * KP + col] = (col < DIN) ? (unsigned short)f2b(v) : 0;
      }
    }
  }
}

// ---------------------------------------------------------------------------
// logits partials: LP[z][m][n] = sum_{k in chunk z} Q[m,k]*K[n,k]
// ---------------------------------------------------------------------------
__global__ __launch_bounds__(512)
void gemm_logits(const unsigned short* __restrict__ Qbf,
                 const unsigned short* __restrict__ Kbf, float* __restrict__ LP)
{
  const int qr = blockIdx.x & 1, qc = blockIdx.x >> 1, z = blockIdx.z;
  const int tid = threadIdx.x, lane = tid & 63, wv = tid >> 6;
  const int lm = lane & 15, lq = (lane >> 4) * 8;
  const int rowBase = qr * 128 + (wv & 3) * 32;
  const int colBase = qc * 128 + (wv >> 2) * 64;
  const int k0 = z * 128;
  f32x4 acc[2][4] = {};
#pragma unroll
  for (int ks = 0; ks < 4; ++ks) {
    bf16x8 a[2], b[4];
#pragma unroll
    for (int i = 0; i < 2; ++i)
      a[i] = *(const bf16x8*)(Qbf + (size_t)(rowBase + i * 16 + lm) * KP + k0 + ks * 32 + lq);
#pragma unroll
    for (int j = 0; j < 4; ++j)
      b[j] = *(const bf16x8*)(Kbf + (size_t)(colBase + j * 16 + lm) * KP + k0 + ks * 32 + lq);
#pragma unroll
    for (int i = 0; i < 2; ++i)
#pragma unroll
      for (int j = 0; j < 4; ++j)
        acc[i][j] = __builtin_amdgcn_mfma_f32_16x16x32_bf16(a[i], b[j], acc[i][j], 0, 0, 0);
  }
  float* out = LP + (size_t)z * 65536;
#pragma unroll
  for (int i = 0; i < 2; ++i) {
    const int r0 = rowBase + i * 16 + (lane >> 4) * 4;
#pragma unroll
    for (int j = 0; j < 4; ++j) {
      const int col = colBase + j * 16 + lm;
#pragma unroll
      for (int q = 0; q < 4; ++q)
        out[(size_t)(r0 + q) * 256 + col] = acc[i][j][q];
    }
  }
}

// ---------------------------------------------------------------------------
// fused: sum 64 logit partials -> row softmax -> atomicAdd into abar (w/ 1/256)
// ---------------------------------------------------------------------------
__global__ void softmax_fused(const float* __restrict__ LP, float* __restrict__ abar)
{
  __shared__ float red[8];
  const int m = blockIdx.x, t = threadIdx.x;
  float v = 0.f;
#pragma unroll 8
  for (int zz = 0; zz < 64; ++zz) v += LP[(size_t)zz * 65536 + m * 256 + t];
  const float scale = 1.0f / sqrtf((float)DIN);
  float mx = v;
#pragma unroll
  for (int o = 32; o >= 1; o >>= 1) mx = fmaxf(mx, __shfl_xor(mx, o, 64));
  if ((t & 63) == 0) red[t >> 6] = mx;
  __syncthreads();
  mx = fmaxf(fmaxf(red[0], red[1]), fmaxf(red[2], red[3]));
  float e = __expf((v - mx) * scale);
  float s = e;
#pragma unroll
  for (int o = 32; o >= 1; o >>= 1) s += __shfl_xor(s, o, 64);
  if ((t & 63) == 0) red[4 + (t >> 6)] = s;
  __syncthreads();
  s = red[4] + red[5] + red[6] + red[7];
  atomicAdd(&abar[t], e * (1.0f / 256.0f) / s);
}

// y[c] = sum_m abar[m] * X[m][c]
__global__ void y_kernel(const float* __restrict__ X, const float* __restrict__ abar,
                         float* __restrict__ y)
{
  __shared__ float ab[256];
  ab[threadIdx.x] = abar[threadIdx.x];
  __syncthreads();
  const int c = blockIdx.x * 256 + threadIdx.x;
  if (c >= DIN) return;
  float s = 0.f;
#pragma unroll 8
  for (int m = 0; m < 256; ++m) s += ab[m] * X[(size_t)m * DIN + c];
  y[c] = s;
}

// ctx[d] = Wv[d,:]·y + bv[d] — one row per wave, lane-contiguous float2 stream
__global__ __launch_bounds__(512)
void ctx_mv(const float* __restrict__ Wv, const float* __restrict__ y,
            const float* __restrict__ bv, float* __restrict__ ctx)
{
  const int wv = threadIdx.x >> 6, l = threadIdx.x & 63;
  const int row = blockIdx.x * 8 + wv;
  if (row >= DIN) return;
  const float* wr_ = Wv + (size_t)row * DIN;
  float s = 0.f;
  for (int it = 0; it < 61; ++it) {
    const int k = it * 128 + l * 2;
    if (k < DIN) {
      float2 w2 = *(const float2*)(wr_ + k);
      float2 y2 = *(const float2*)(y + k);
      s = fmaf(w2.x, y2.x, s);
      s = fmaf(w2.y, y2.y, s);
    }
  }
#pragma unroll
  for (int o = 32; o >= 1; o >>= 1) s += __shfl_xor(s, o, 64);
  if (l == 0) ctx[row] = s + bv[row];
}

// base[j] += sum_{i in chunk} ctx[i] * (mu+sg*ep)[i][DIN+j]
__global__ void base_kernel(const float* __restrict__ mu, const float* __restrict__ sg,
                            const float* __restrict__ ep, const float* __restrict__ ctx,
                            float* __restrict__ base)
{
  const int j = threadIdx.x;
  if (j >= HOUT) return;
  const int i0 = blockIdx.x * 31;
  const int i1 = min(i0 + 31, DIN);
  float acc = 0.f;
#pragma unroll 4
  for (int i = i0; i < i1; ++i) {
    const size_t idx = (size_t)i * NNODE + DIN + j;
    acc = fmaf(ctx[i], fmaf(sg[idx], ep[idx], mu[idx]), acc);
  }
  atomicAdd(&base[j], acc);
}

// WsG[t][j] = (mu+sg*ep)[DIN+t][DIN+j]
__global__ void ws_kernel(const float* __restrict__ mu, const float* __restrict__ sg,
                          const float* __restrict__ ep, float* __restrict__ WsG)
{
  const int t = blockIdx.x;
  const int j = threadIdx.x;
  if (j >= HOUT) return;
  const size_t idx = (size_t)(DIN + t) * NNODE + DIN + j;
  WsG[t * HOUT + j] = fmaf(sg[idx], ep[idx], mu[idx]);
}

// ---------------------------------------------------------------------------
// scan2: latency-minimal sequential NEAT scan. 1 wave.
// - register-staged float4 tile prefetch (issued a full tile early)
// - per-step chain: v_readlane -> fast tanh (expf) -> guarded fma
// - W-row LDS values prefetched one step ahead (off critical chain)
// ---------------------------------------------------------------------------
__global__ __launch_bounds__(64, 1)
void scan2(const float* __restrict__ WsG, const float* __restrict__ base,
           const float* __restrict__ bmu, const float* __restrict__ bsg,
           const float* __restrict__ epb, float* __restrict__ out)
{
  __shared__ __align__(16) float tile[32 * HOUT + 128];
  const int l = threadIdx.x;

  float a0, a1, a2, a3, a4;
  {
    int j = l;       a0 = base[j] + bmu[j] + bsg[j] * epb[j];
    j = l + 64;      a1 = base[j] + bmu[j] + bsg[j] * epb[j];
    j = l + 128;     a2 = base[j] + bmu[j] + bsg[j] * epb[j];
    j = l + 192;     a3 = base[j] + bmu[j] + bsg[j] * epb[j];
    j = l + 256;     a4 = (j < HOUT) ? (base[j] + bmu[j] + bsg[j] * epb[j]) : 0.f;
  }

  float4 stg[33];
  auto LOADT = [&](int tb) {           // issue wide loads for tile tb into regs
    const int nfl = ((tb == 8) ? 4 : 32) * HOUT;
    const float* src = WsG + tb * 32 * HOUT;
#pragma unroll
    for (int c = 0; c < 33; ++c) {
      const int o = c * 256 + l * 4;
      if (o < nfl) stg[c] = *(const float4*)(src + o);
    }
  };
  auto WRITET = [&](int tb) {          // regs -> LDS (vmcnt satisfied by now)
    const int nfl = ((tb == 8) ? 4 : 32) * HOUT;
#pragma unroll
    for (int c = 0; c < 33; ++c) {
      const int o = c * 256 + l * 4;
      if (o < nfl) *(float4*)&tile[o] = stg[c];
    }
  };

  float w0, w1, w2, w3, w4;
  auto PRER = [&](int trow) {          // prefetch W[t][j] for this lane's 5 js
    const float* tr = tile + trow * HOUT;
    w0 = tr[l]; w1 = tr[l + 64]; w2 = tr[l + 128]; w3 = tr[l + 192]; w4 = tr[l + 256];
  };

  auto inner = [&](auto Bc, int tb, int nrows) {
    constexpr int B = Bc.value;
    for (int tt = 0; tt < nrows; ++tt) {
      const int t = tb * 32 + tt;
      float pre;
      if constexpr (B == 0) pre = readlane_f(a0, t & 63);
      else if constexpr (B == 1) pre = readlane_f(a1, t & 63);
      else if constexpr (B == 2) pre = readlane_f(a2, t & 63);
      else if constexpr (B == 3) pre = readlane_f(a3, t & 63);
      else pre = readlane_f(a4, t & 63);
      const float pc = fminf(fmaxf(pre, -12.f), 12.f);
      const float e = __expf(2.f * pc);
      const float vt = 1.f - 2.f / (e + 1.f);     // tanh(pre)
      if (t >= 256 && l == 0) out[t - 256] = vt;
      // guarded rank-1 update with prefetched W row t
      if (l > t)            a0 = fmaf(vt, w0, a0);
      if (l + 64 > t)       a1 = fmaf(vt, w1, a1);
      if (l + 128 > t)      a2 = fmaf(vt, w2, a2);
      if (l + 192 > t)      a3 = fmaf(vt, w3, a3);
      if (l + 256 > t && l + 256 < HOUT) a4 = fmaf(vt, w4, a4);
      if (tt + 1 < nrows) PRER(tt + 1);           // off-chain prefetch
    }
  };

  // prologue: tile 0 staged directly
  LOADT(0); WRITET(0); PRER(0);

#define TILE_STEP(tb, B, nr)                                    \
  { if ((tb) < 8) LOADT((tb) + 1);                              \
    inner(std::integral_constant<int, B>{}, (tb), (nr));        \
    if ((tb) < 8) { WRITET((tb) + 1); PRER(0); } }

  TILE_STEP(0, 0, 32)
  TILE_STEP(1, 0, 32)
  TILE_STEP(2, 1, 32)
  TILE_STEP(3, 1, 32)
  TILE_STEP(4, 2, 32)
  TILE_STEP(5, 2, 32)
  TILE_STEP(6, 3, 32)
  TILE_STEP(7, 3, 32)
  TILE_STEP(8, 4, 4)
#undef TILE_STEP
}

// ---------------------------------------------------------------------------
extern "C" void kernel_launch(void* const* d_in, const int* in_sizes, int n_in,
                              void* d_out, int out_size, void* d_ws, size_t ws_size,
                              hipStream_t stream)
{
  const float* X   = (const float*)d_in[0];
  const float* Wq  = (const float*)d_in[1];
  const float* bq  = (const float*)d_in[2];
  const float* Wk  = (const float*)d_in[3];
  const float* bk  = (const float*)d_in[4];
  const float* Wv  = (const float*)d_in[5];
  const float* bv  = (const float*)d_in[6];
  const float* wmu = (const float*)d_in[7];
  const float* wsg = (const float*)d_in[8];
  const float* bmu = (const float*)d_in[9];
  const float* bsg = (const float*)d_in[10];
  const float* epw = (const float*)d_in[11];
  const float* epb = (const float*)d_in[12];

  char* p = (char*)d_ws;
  auto alloc = [&](size_t bytes) -> char* {
    char* r = p;
    p += (bytes + 255) & ~(size_t)255;
    return r;
  };
  unsigned short* XbT = (unsigned short*)alloc((size_t)64 * 65536);
  unsigned short* Qbf = (unsigned short*)alloc((size_t)256 * KP * 2);
  unsigned short* Kbf = (unsigned short*)alloc((size_t)256 * KP * 2);
  float* LP   = (float*)alloc((size_t)64 * 65536 * 4);
  float* abar = (float*)alloc(256 * 4);
  float* y    = (float*)alloc(7686 * 4);
  float* ctx  = (float*)alloc(7686 * 4);
  float* base = (float*)alloc(HOUT * 4);
  float* WsG  = (float*)alloc((size_t)HOUT * HOUT * 4 + 1024);

  prep_x<<<dim3(256), dim3(256), 0, stream>>>(X, XbT);
  hipMemsetAsync(abar, 0, 256 * 4, stream);
  hipMemsetAsync(base, 0, HOUT * 4, stream);
  hipMemsetAsync(Qbf, 0, (size_t)256 * KP * 2, stream);
  hipMemsetAsync(Kbf, 0, (size_t)256 * KP * 2, stream);

  gemm_qk2<<<dim3(121, 2), dim3(512), 0, stream>>>(XbT, Wq, Wk, bq, bk, Qbf, Kbf);
  gemm_logits<<<dim3(4, 1, 64), dim3(512), 0, stream>>>(Qbf, Kbf, LP);
  softmax_fused<<<dim3(256), dim3(256), 0, stream>>>(LP, abar);
  y_kernel<<<dim3(31), dim3(256), 0, stream>>>(X, abar, y);
  ctx_mv<<<dim3(961), dim3(512), 0, stream>>>(Wv, y, bv, ctx);
  base_kernel<<<dim3(256), dim3(320), 0, stream>>>(wmu, wsg, epw, ctx, base);
  ws_kernel<<<dim3(260), dim3(320), 0, stream>>>(wmu, wsg, epw, WsG);
  scan2<<<dim3(1), dim3(64), 0, stream>>>(WsG, base, bmu, bsg, epb, (float*)d_out);
}